// Round 12
// baseline (160.653 us; speedup 1.0000x reference)
//
#include <hip/hip_runtime.h>
#include <cstdint>
#include <cstddef>

#define B_   128
#define NF_  64
#define L_   4096
#define K_   64
#define NG_  400

#define GP_     8                 // g partitions (grid.x): 512 blocks = 2/CU
#define GITER_  (NG_ / GP_)       // 50 g-tiles per block
#define ROWS_   2                 // batch rows per block (weight amortization)
#define PADF_   64                // zero pad each side (win-128 overhang <= 64)
#define ROWPF_  (PADF_ + L_ + PADF_)   // 4224 floats per padded row

constexpr float STEP = 4096.0f / 4095.0f;              // linspace(0,4096,4096) step
constexpr float NEGC = -1.4426950408889634f / 512.0f;  // -log2(e)/(2*sigma^2), sigma=16

// ---------------------------------------------------------------------------
// R11 structure (reg-staged dbuf LDS, one __syncthreads per tile, 1024 thr,
// 32 waves/CU) with the Gaussian window cut 192 -> 128 samples (+-64, tail
// error ~3e-6 on filtered, far under threshold). Cuts exp2 12->8, ds_read
// 6->4, dot-fma 24->16 per thread-iter: trans/VALU/LDS issue pressure drops
// ~33% so the co-schedule can keep the HBM queue full.
// 64 filters x 16 lanes; each lane owns 2 float4 slots of the 128-window.
// ---------------------------------------------------------------------------
__global__ __launch_bounds__(1024, 8) void filt_kernel(
    const float* __restrict__ X, const float* __restrict__ mus,
    const float* __restrict__ amps, float* __restrict__ part)
{
    const int p   = blockIdx.x;
    const int b0  = blockIdx.y * ROWS_;
    const int t   = threadIdx.x;
    const int f   = t >> 4;       // filter 0..63
    const int i16 = t & 15;       // window float4 slot 0..15 (2 f4 each)

    __shared__ __align__(16) float Xs[2][ROWS_][ROWPF_];

    // zero the pads of both buffers once (16 f4 front + 16 f4 back per row)
    if (t < 128) {
        const int br = t >> 5;            // (buf,row) 0..3
        const int k  = t & 31;
        float4* pr = (float4*)Xs[br >> 1][br & 1];
        const float4 z{0.f, 0.f, 0.f, 0.f};
        if (k < 16) pr[k] = z;
        else        pr[1040 + (k - 16)] = z;   // (PADF_+L_)/4 = 1040
    }

    const float* __restrict__ Xb0 = X + ((size_t)(b0 + 0) * NG_) * L_;
    const float* __restrict__ Xb1 = X + ((size_t)(b0 + 1) * NG_) * L_;
    const int gs = p * GITER_;

    // ---- prologue: tile 0 -> LDS[0]; mu/sc(g0) in regs ----
    float4 xv0 = ((const float4*)(Xb0 + (size_t)gs * L_))[t];
    float4 xv1 = ((const float4*)(Xb1 + (size_t)gs * L_))[t];
    float mu_c = mus [f * NG_ + gs];
    float sc_c = amps[f * NG_ + gs] * (1.0f / 4096.0f);
    ((float4*)(Xs[0][0] + PADF_))[t] = xv0;
    ((float4*)(Xs[0][1] + PADF_))[t] = xv1;
    __syncthreads();

    float acc0 = 0.f, acc1 = 0.f;

    for (int it = 0; it < GITER_; ++it) {
        const int  cur  = it & 1;
        const bool more = (it + 1 < GITER_);
        const int  g    = gs + it;

        // issue next tile's loads FIRST (latency hides under compute)
        if (more) {
            xv0 = ((const float4*)(Xb0 + (size_t)(g + 1) * L_))[t];
            xv1 = ((const float4*)(Xb1 + (size_t)(g + 1) * L_))[t];
        }
        const float mu = mu_c;
        const float sc = sc_c;
        if (more) {                       // one-iter-ahead scalar prefetch
            mu_c = mus [f * NG_ + g + 1];
            sc_c = amps[f * NG_ + g + 1] * (1.0f / 4096.0f);
        }

        // 8 Gaussian window weights + windowed dot for both rows.
        // 16 consecutive lanes read 16 consecutive float4 (256B) -> each
        // bank exactly twice = free 2-way aliasing (m136).
        const int   l0 = (((int)mu) - 64) & ~3;        // 16B-aligned start
        const float bx = fmaf((float)(l0 + 4 * i16), STEP, -mu);
        const float* x0 = Xs[cur][0] + PADF_ + l0 + 4 * i16;
        const float* x1 = Xs[cur][1] + PADF_ + l0 + 4 * i16;
        float d0 = 0.f, d1 = 0.f;
#pragma unroll
        for (int c = 0; c < 2; ++c) {
            float w[4];
#pragma unroll
            for (int j = 0; j < 4; ++j) {
                const float d = bx + (float)(64 * c + j) * STEP;
                w[j] = exp2f(NEGC * d * d);
            }
            const float4 a = *(const float4*)(x0 + 64 * c);
            const float4 b = *(const float4*)(x1 + 64 * c);
            d0 = fmaf(a.x, w[0], fmaf(a.y, w[1], fmaf(a.z, w[2], fmaf(a.w, w[3], d0))));
            d1 = fmaf(b.x, w[0], fmaf(b.y, w[1], fmaf(b.z, w[2], fmaf(b.w, w[3], d1))));
        }
        acc0 = fmaf(sc, d0, acc0);
        acc1 = fmaf(sc, d1, acc1);

        // write next tile, single barrier (R4-proven)
        if (more) {
            ((float4*)(Xs[cur ^ 1][0] + PADF_))[t] = xv0;
            ((float4*)(Xs[cur ^ 1][1] + PADF_))[t] = xv1;
            __syncthreads();
        }
    }

    // reduce across the 16 consecutive lanes sharing this filter
#pragma unroll
    for (int d = 1; d < 16; d <<= 1) {
        acc0 += __shfl_xor(acc0, d);
        acc1 += __shfl_xor(acc1, d);
    }
    if (i16 == 0) {
        part[((size_t)p * B_ + b0    ) * NF_ + f] = acc0;
        part[((size_t)p * B_ + b0 + 1) * NF_ + f] = acc1;
    }
}

// ---------------------------------------------------------------------------
// MLP head: sums GP_ partials, elu/reparam + 3 small GEMVs (exact gelu).
// grid (B_, 4): q-slice owns 100 of 400 output gaussians; front recomputed
// per slice, q==0 stores mu/log_sig.
// out layout: coms[128*400] | pred[128*400] | mu[128*64] | log_sig[128*64]
// ---------------------------------------------------------------------------
__device__ __forceinline__ float gelu_exact(float x) {
    return 0.5f * x * (1.0f + erff(x * 0.70710678118654752f));
}

__global__ __launch_bounds__(256) void head_kernel(
    const float* __restrict__ part, const float* __restrict__ eps,
    const float* __restrict__ Wmu,  const float* __restrict__ bmu,
    const float* __restrict__ Wsig, const float* __restrict__ bsig,
    const float* __restrict__ W01,  const float* __restrict__ b01,
    const float* __restrict__ W1,   const float* __restrict__ b1,
    const float* __restrict__ W2,   const float* __restrict__ b2,
    float* __restrict__ out)
{
    const int b = blockIdx.x;
    const int q = blockIdx.y;
    const int t = threadIdx.x;
    __shared__ float fil[NF_], lat[K_], hh[K_];

    if (t < NF_) {
        float s = 0.f;
#pragma unroll
        for (int pp = 0; pp < GP_; ++pp)
            s += part[((size_t)pp * B_ + b) * NF_ + t];
        fil[t] = s;
    }
    __syncthreads();

    if (t < K_) {
        float am = bmu[t], as = bsig[t];
#pragma unroll 8
        for (int fj = 0; fj < NF_; ++fj) {
            float x = fil[fj];
            am = fmaf(x, Wmu [t * NF_ + fj], am);
            as = fmaf(x, Wsig[t * NF_ + fj], as);
        }
        float muv = am > 0.0f ? am : expm1f(am);
        float lsv = as > 0.0f ? as : expm1f(as);
        if (q == 0) {
            out[2 * B_ * NG_            + b * K_ + t] = muv;   // mu
            out[2 * B_ * NG_ + B_ * K_  + b * K_ + t] = lsv;   // log_sig
        }
        lat[t] = fmaf(eps[b * K_ + t], expf(lsv), muv);
    }
    __syncthreads();

    if (t < K_) {
        float a = b01[t];
#pragma unroll 8
        for (int j = 0; j < K_; ++j) a = fmaf(lat[j], W01[t * K_ + j], a);
        hh[t] = gelu_exact(a);
    }
    __syncthreads();

    const int n0 = q * 100, n1 = n0 + 100;
    for (int n = n0 + t; n < n1; n += 256) {
        float a1 = b1[n], a2 = b2[n];
#pragma unroll 8
        for (int k = 0; k < K_; ++k) {
            float hk = hh[k];
            a1 = fmaf(hk, W1[n * K_ + k], a1);
            a2 = fmaf(hk, W2[n * K_ + k], a2);
        }
        out[            b * NG_ + n] = gelu_exact(a1);   // coms
        out[B_ * NG_ +  b * NG_ + n] = gelu_exact(a2);   // pred_num_spikes
    }
}

extern "C" void kernel_launch(void* const* d_in, const int* in_sizes, int n_in,
                              void* d_out, int out_size, void* d_ws, size_t ws_size,
                              hipStream_t stream) {
    const float* X    = (const float*)d_in[0];
    const float* eps  = (const float*)d_in[1];
    const float* mus  = (const float*)d_in[2];
    const float* amps = (const float*)d_in[3];
    const float* Wmu  = (const float*)d_in[4];
    const float* bmu  = (const float*)d_in[5];
    const float* Wsig = (const float*)d_in[6];
    const float* bsig = (const float*)d_in[7];
    const float* W01  = (const float*)d_in[8];
    const float* b01  = (const float*)d_in[9];
    const float* W1   = (const float*)d_in[10];
    const float* b1   = (const float*)d_in[11];
    const float* W2   = (const float*)d_in[12];
    const float* b2   = (const float*)d_in[13];

    float* out  = (float*)d_out;
    float* part = (float*)d_ws;   // GP_*B_*NF_ f32 partials (fully overwritten)

    filt_kernel<<<dim3(GP_, B_ / ROWS_), 1024, 0, stream>>>(X, mus, amps, part);
    head_kernel<<<dim3(B_, 4), 256, 0, stream>>>(part, eps, Wmu, bmu, Wsig, bsig,
                                                 W01, b01, W1, b1, W2, b2, out);
}